// Round 1
// baseline (491.914 us; speedup 1.0000x reference)
//
#include <hip/hip_runtime.h>

// ---------------------------------------------------------------------------
// GAT (3 layers) + attention pooling + regressor, full f32.
// N=20000 nodes, E=320000 edges (+N self loops), H=4 heads, C=64, B=16 graphs.
// ---------------------------------------------------------------------------

// ---------------- CSR-by-destination build ----------------
__global__ void edge_hist_k(const int* __restrict__ ei, int E, int n, int* __restrict__ deg) {
    int i = blockIdx.x * blockDim.x + threadIdx.x;
    if (i >= E + n) return;
    int dst = (i < E) ? ei[E + i] : (i - E);   // self-loop for i >= E
    atomicAdd(&deg[dst], 1);
}

__global__ void scan_excl_k(const int* __restrict__ deg, int* __restrict__ rowptr,
                            int* __restrict__ cursor, int n) {
    __shared__ int part[256];
    int tid = threadIdx.x;
    int chunk = (n + 255) / 256;
    int lo = tid * chunk;
    int hi = lo + chunk;
    if (lo > n) lo = n;
    if (hi > n) hi = n;
    int s = 0;
    for (int i = lo; i < hi; ++i) s += deg[i];
    part[tid] = s;
    __syncthreads();
    for (int off = 1; off < 256; off <<= 1) {
        int v = (tid >= off) ? part[tid - off] : 0;
        __syncthreads();
        part[tid] += v;
        __syncthreads();
    }
    int run = (tid == 0) ? 0 : part[tid - 1];
    for (int i = lo; i < hi; ++i) {
        rowptr[i] = run;
        cursor[i] = run;
        run += deg[i];
    }
    if (tid == 255) rowptr[n] = run;
}

__global__ void edge_scatter_k(const int* __restrict__ ei, int E, int n,
                               int* __restrict__ cursor, int* __restrict__ srcs) {
    int i = blockIdx.x * blockDim.x + threadIdx.x;
    if (i >= E + n) return;
    int src, dst;
    if (i < E) { src = ei[i]; dst = ei[E + i]; }
    else       { src = i - E; dst = src; }
    int pos = atomicAdd(&cursor[dst], 1);
    srcs[pos] = src;
}

// ---------------- f32 tiled GEMM: C[M,Nn] = A[M,K] @ B[K,Nn] ----------------
// 256 threads, block tile 128x64, BK=16, per-thread 8x4 micro-tile.
__global__ __launch_bounds__(256) void gemm_f32_k(const float* __restrict__ A,
                                                  const float* __restrict__ B,
                                                  float* __restrict__ C,
                                                  int M, int Nn, int K) {
    __shared__ float As[16][128];   // A transposed: As[k][m]
    __shared__ float Bs[16][64];
    const int tid = threadIdx.x;
    const int m0 = blockIdx.x * 128;
    const int n0 = blockIdx.y * 64;
    const int tm = tid >> 4;        // 0..15
    const int tn = tid & 15;        // 0..15
    float acc[8][4];
#pragma unroll
    for (int i = 0; i < 8; ++i)
#pragma unroll
        for (int j = 0; j < 4; ++j) acc[i][j] = 0.f;

    for (int k0 = 0; k0 < K; k0 += 16) {
        // stage A tile (128 rows x 16 k), transposed into LDS
#pragma unroll
        for (int i = 0; i < 2; ++i) {
            int f = tid * 2 + i;            // 0..511 float4 slots
            int r = f >> 2;                 // row in tile 0..127
            int kq = (f & 3) << 2;          // k offset 0,4,8,12
            int row = m0 + r;
            float4 v = make_float4(0.f, 0.f, 0.f, 0.f);
            if (row < M) v = *reinterpret_cast<const float4*>(&A[(size_t)row * K + k0 + kq]);
            As[kq + 0][r] = v.x;
            As[kq + 1][r] = v.y;
            As[kq + 2][r] = v.z;
            As[kq + 3][r] = v.w;
        }
        // stage B tile (16 x 64)
        {
            int kk = tid >> 4;
            int cq = (tid & 15) << 2;
            *reinterpret_cast<float4*>(&Bs[kk][cq]) =
                *reinterpret_cast<const float4*>(&B[(size_t)(k0 + kk) * Nn + n0 + cq]);
        }
        __syncthreads();
#pragma unroll
        for (int k = 0; k < 16; ++k) {
            float4 a0 = *reinterpret_cast<const float4*>(&As[k][tm * 8]);
            float4 a1 = *reinterpret_cast<const float4*>(&As[k][tm * 8 + 4]);
            float4 bv = *reinterpret_cast<const float4*>(&Bs[k][tn * 4]);
            float a[8] = {a0.x, a0.y, a0.z, a0.w, a1.x, a1.y, a1.z, a1.w};
            float b[4] = {bv.x, bv.y, bv.z, bv.w};
#pragma unroll
            for (int i = 0; i < 8; ++i)
#pragma unroll
                for (int j = 0; j < 4; ++j) acc[i][j] = fmaf(a[i], b[j], acc[i][j]);
        }
        __syncthreads();
    }
#pragma unroll
    for (int i = 0; i < 8; ++i) {
        int row = m0 + tm * 8 + i;
        if (row < M) {
            float4 v = make_float4(acc[i][0], acc[i][1], acc[i][2], acc[i][3]);
            *reinterpret_cast<float4*>(&C[(size_t)row * Nn + n0 + tn * 4]) = v;
        }
    }
}

// ---------------- per-(node,head) attention scalars ----------------
template <int HEADS>
__global__ void attn_scores_k(const float* __restrict__ hin, const float* __restrict__ a_src,
                              const float* __restrict__ a_dst, float* __restrict__ esrc,
                              float* __restrict__ edst, int n) {
    int wid = blockIdx.x * (blockDim.x >> 6) + (threadIdx.x >> 6);
    int lane = threadIdx.x & 63;
    if (wid >= n * HEADS) return;
    int node = wid / HEADS;
    int h = wid - node * HEADS;
    float hv = hin[(size_t)node * (HEADS * 64) + h * 64 + lane];
    float vs = hv * a_src[h * 64 + lane];
    float vd = hv * a_dst[h * 64 + lane];
#pragma unroll
    for (int off = 32; off; off >>= 1) {
        vs += __shfl_xor(vs, off);
        vd += __shfl_xor(vd, off);
    }
    if (lane == 0) { esrc[wid] = vs; edst[wid] = vd; }
}

// ---------------- GAT aggregation (softmax + weighted gather) ----------------
// One block per destination node; thread = (head, channel). Softmax computed
// without max-subtraction (logits provably tiny => mathematically identical).
template <int HEADS>
__global__ void gat_aggregate_k(const float* __restrict__ hin, const float* __restrict__ esrc,
                                const float* __restrict__ edst, const int* __restrict__ rowptr,
                                const int* __restrict__ srcs, const float* __restrict__ bias,
                                float* __restrict__ gout, int n) {
    const int HC = HEADS * 64;
    int d = blockIdx.x;
    int tid = threadIdx.x;
    int h = tid >> 6;
    float ed = edst[d * HEADS + h];
    int lo = rowptr[d], hi = rowptr[d + 1];
    float den = 0.f, acc = 0.f;
    for (int i = lo; i < hi; ++i) {
        int s = srcs[i];
        float e = esrc[s * HEADS + h] + ed;
        e = (e >= 0.f) ? e : 0.2f * e;           // leaky_relu(0.2)
        float w = __expf(e);
        den += w;
        acc += w * hin[(size_t)s * HC + tid];
    }
    float o = acc / den + bias[tid];
    o = (o > 0.f) ? o : expm1f(o);               // ELU
    gout[(size_t)d * HC + tid] = o;
}

// ---------------- node attention gate ----------------
__global__ void node_attn_k(const float* __restrict__ g3, const float* __restrict__ wp,
                            const float* __restrict__ bp, float* __restrict__ attn, int n) {
    int wid = blockIdx.x * (blockDim.x >> 6) + (threadIdx.x >> 6);
    int lane = threadIdx.x & 63;
    if (wid >= n) return;
    float v = g3[(size_t)wid * 64 + lane] * wp[lane];
#pragma unroll
    for (int off = 32; off; off >>= 1) v += __shfl_xor(v, off);
    if (lane == 0) attn[wid] = 1.f / (1.f + __expf(-(v + bp[0])));
}

// ---------------- per-graph mean pool + regressor ----------------
__global__ void pool_regress_k(const float* __restrict__ g3, const float* __restrict__ attn,
                               const int* __restrict__ batch, int n,
                               const float* __restrict__ wr, const float* __restrict__ br,
                               float* __restrict__ out) {
    int b = blockIdx.x;
    int tid = threadIdx.x;
    // binary search segment [seg_lo, seg_hi) in sorted batch
    int lo = 0, hi = n;
    while (lo < hi) { int mid = (lo + hi) >> 1; if (batch[mid] < b) lo = mid + 1; else hi = mid; }
    int seg_lo = lo;
    lo = 0; hi = n;
    while (lo < hi) { int mid = (lo + hi) >> 1; if (batch[mid] < b + 1) lo = mid + 1; else hi = mid; }
    int seg_hi = lo;

    int c = tid & 63, j = tid >> 6;
    float acc = 0.f;
    for (int i = seg_lo + j; i < seg_hi; i += 4) acc += g3[(size_t)i * 64 + c] * attn[i];
    __shared__ float red[256];
    red[tid] = acc;
    __syncthreads();
    if (tid < 64) {
        float s = red[tid] + red[tid + 64] + red[tid + 128] + red[tid + 192];
        float cnt = (float)(seg_hi - seg_lo);
        if (cnt < 1.f) cnt = 1.f;
        float v = (s / cnt) * wr[tid];
#pragma unroll
        for (int off = 32; off; off >>= 1) v += __shfl_xor(v, off);
        if (tid == 0) out[b] = v + br[0];
    }
}

// ---------------------------------------------------------------------------
extern "C" void kernel_launch(void* const* d_in, const int* in_sizes, int n_in,
                              void* d_out, int out_size, void* d_ws, size_t ws_size,
                              hipStream_t stream) {
    const float* x   = (const float*)d_in[0];
    const int*   ei  = (const int*)d_in[1];
    const int*   bat = (const int*)d_in[2];
    const float* W1  = (const float*)d_in[3];
    const float* as1 = (const float*)d_in[4];
    const float* ad1 = (const float*)d_in[5];
    const float* b1  = (const float*)d_in[6];
    const float* W2  = (const float*)d_in[7];
    const float* as2 = (const float*)d_in[8];
    const float* ad2 = (const float*)d_in[9];
    const float* b2  = (const float*)d_in[10];
    const float* W3  = (const float*)d_in[11];
    const float* as3 = (const float*)d_in[12];
    const float* ad3 = (const float*)d_in[13];
    const float* b3  = (const float*)d_in[14];
    const float* wp  = (const float*)d_in[15];
    const float* bp  = (const float*)d_in[16];
    const float* wr  = (const float*)d_in[17];
    const float* br  = (const float*)d_in[18];
    float* out = (float*)d_out;

    const int N    = in_sizes[2];          // 20000
    const int E    = in_sizes[1] / 2;      // 320000
    const int DIN  = in_sizes[0] / N;      // 128
    const int Etot = E + N;
    const int Bc   = out_size;             // 16

    char* ws = (char*)d_ws;
    size_t off = 0;
    auto alloc = [&](size_t bytes) {
        void* p = ws + off;
        off = (off + bytes + 255) & ~(size_t)255;
        return p;
    };
    int*   deg    = (int*)alloc((size_t)N * 4);
    int*   rowptr = (int*)alloc((size_t)(N + 1) * 4);
    int*   cursor = (int*)alloc((size_t)N * 4);
    int*   srcs   = (int*)alloc((size_t)Etot * 4);
    float* bufA   = (float*)alloc((size_t)N * 256 * 4);   // h1, then h2
    float* bufB   = (float*)alloc((size_t)N * 256 * 4);   // g1, then g2
    float* h3     = (float*)alloc((size_t)N * 64 * 4);
    float* g3     = (float*)alloc((size_t)N * 64 * 4);
    float* esrc   = (float*)alloc((size_t)N * 4 * 4);
    float* edst   = (float*)alloc((size_t)N * 4 * 4);
    float* attn   = (float*)alloc((size_t)N * 4);
    (void)ws_size;

    // CSR build (shared by all layers)
    hipMemsetAsync(deg, 0, (size_t)N * 4, stream);
    int eb = (Etot + 255) / 256;
    edge_hist_k<<<eb, 256, 0, stream>>>(ei, E, N, deg);
    scan_excl_k<<<1, 256, 0, stream>>>(deg, rowptr, cursor, N);
    edge_scatter_k<<<eb, 256, 0, stream>>>(ei, E, N, cursor, srcs);

    dim3 gemm_grid1((N + 127) / 128, 256 / 64);
    dim3 gemm_grid3((N + 127) / 128, 1);

    // Layer 1: DIN -> (4,64) concat
    gemm_f32_k<<<gemm_grid1, 256, 0, stream>>>(x, W1, bufA, N, 256, DIN);
    attn_scores_k<4><<<(N * 4 + 3) / 4, 256, 0, stream>>>(bufA, as1, ad1, esrc, edst, N);
    gat_aggregate_k<4><<<N, 256, 0, stream>>>(bufA, esrc, edst, rowptr, srcs, b1, bufB, N);

    // Layer 2: 256 -> (4,64) concat
    gemm_f32_k<<<gemm_grid1, 256, 0, stream>>>(bufB, W2, bufA, N, 256, 256);
    attn_scores_k<4><<<(N * 4 + 3) / 4, 256, 0, stream>>>(bufA, as2, ad2, esrc, edst, N);
    gat_aggregate_k<4><<<N, 256, 0, stream>>>(bufA, esrc, edst, rowptr, srcs, b2, bufB, N);

    // Layer 3: 256 -> (1,64) mean (== identity over 1 head)
    gemm_f32_k<<<gemm_grid3, 256, 0, stream>>>(bufB, W3, h3, N, 64, 256);
    attn_scores_k<1><<<(N + 3) / 4, 256, 0, stream>>>(h3, as3, ad3, esrc, edst, N);
    gat_aggregate_k<1><<<N, 64, 0, stream>>>(h3, esrc, edst, rowptr, srcs, b3, g3, N);

    // Attention pool + regressor
    node_attn_k<<<(N + 3) / 4, 256, 0, stream>>>(g3, wp, bp, attn, N);
    pool_regress_k<<<Bc, 256, 0, stream>>>(g3, attn, bat, N, wr, br, out);
}

// Round 2
// 425.601 us; speedup vs baseline: 1.1558x; 1.1558x over previous
//
#include <hip/hip_runtime.h>

// ---------------------------------------------------------------------------
// GAT (3 layers) + attention pooling + regressor, full f32.
// N=20000 nodes, E=320000 edges (+N self loops), H=4 heads, C=64, B=16 graphs.
// ---------------------------------------------------------------------------

// ---------------- CSR-by-destination build ----------------
__global__ void edge_hist_k(const int* __restrict__ ei, int E, int n, int* __restrict__ deg) {
    int i = blockIdx.x * blockDim.x + threadIdx.x;
    if (i >= E + n) return;
    int dst = (i < E) ? ei[E + i] : (i - E);   // self-loop for i >= E
    atomicAdd(&deg[dst], 1);
}

__global__ void scan_excl_k(const int* __restrict__ deg, int* __restrict__ rowptr,
                            int* __restrict__ cursor, int n) {
    __shared__ int part[256];
    int tid = threadIdx.x;
    int chunk = (n + 255) / 256;
    int lo = tid * chunk;
    int hi = lo + chunk;
    if (lo > n) lo = n;
    if (hi > n) hi = n;
    int s = 0;
    for (int i = lo; i < hi; ++i) s += deg[i];
    part[tid] = s;
    __syncthreads();
    for (int off = 1; off < 256; off <<= 1) {
        int v = (tid >= off) ? part[tid - off] : 0;
        __syncthreads();
        part[tid] += v;
        __syncthreads();
    }
    int run = (tid == 0) ? 0 : part[tid - 1];
    for (int i = lo; i < hi; ++i) {
        rowptr[i] = run;
        cursor[i] = run;
        run += deg[i];
    }
    if (tid == 255) rowptr[n] = run;
}

__global__ void edge_scatter_k(const int* __restrict__ ei, int E, int n,
                               int* __restrict__ cursor, int* __restrict__ srcs) {
    int i = blockIdx.x * blockDim.x + threadIdx.x;
    if (i >= E + n) return;
    int src, dst;
    if (i < E) { src = ei[i]; dst = ei[E + i]; }
    else       { src = i - E; dst = src; }
    int pos = atomicAdd(&cursor[dst], 1);
    srcs[pos] = src;
}

// ---------------- f32 tiled GEMM: C[M,Nn] = A[M,K] @ B[K,Nn] ----------------
// 256 threads, block tile 128x64, BK=16, per-thread 8x4 micro-tile.
__global__ __launch_bounds__(256) void gemm_f32_k(const float* __restrict__ A,
                                                  const float* __restrict__ B,
                                                  float* __restrict__ C,
                                                  int M, int Nn, int K) {
    __shared__ float As[16][128];   // A transposed: As[k][m]
    __shared__ float Bs[16][64];
    const int tid = threadIdx.x;
    const int m0 = blockIdx.x * 128;
    const int n0 = blockIdx.y * 64;
    const int tm = tid >> 4;        // 0..15
    const int tn = tid & 15;        // 0..15
    float acc[8][4];
#pragma unroll
    for (int i = 0; i < 8; ++i)
#pragma unroll
        for (int j = 0; j < 4; ++j) acc[i][j] = 0.f;

    for (int k0 = 0; k0 < K; k0 += 16) {
        // stage A tile (128 rows x 16 k), transposed into LDS
#pragma unroll
        for (int i = 0; i < 2; ++i) {
            int f = tid * 2 + i;            // 0..511 float4 slots
            int r = f >> 2;                 // row in tile 0..127
            int kq = (f & 3) << 2;          // k offset 0,4,8,12
            int row = m0 + r;
            float4 v = make_float4(0.f, 0.f, 0.f, 0.f);
            if (row < M) v = *reinterpret_cast<const float4*>(&A[(size_t)row * K + k0 + kq]);
            As[kq + 0][r] = v.x;
            As[kq + 1][r] = v.y;
            As[kq + 2][r] = v.z;
            As[kq + 3][r] = v.w;
        }
        // stage B tile (16 x 64)
        {
            int kk = tid >> 4;
            int cq = (tid & 15) << 2;
            *reinterpret_cast<float4*>(&Bs[kk][cq]) =
                *reinterpret_cast<const float4*>(&B[(size_t)(k0 + kk) * Nn + n0 + cq]);
        }
        __syncthreads();
#pragma unroll
        for (int k = 0; k < 16; ++k) {
            float4 a0 = *reinterpret_cast<const float4*>(&As[k][tm * 8]);
            float4 a1 = *reinterpret_cast<const float4*>(&As[k][tm * 8 + 4]);
            float4 bv = *reinterpret_cast<const float4*>(&Bs[k][tn * 4]);
            float a[8] = {a0.x, a0.y, a0.z, a0.w, a1.x, a1.y, a1.z, a1.w};
            float b[4] = {bv.x, bv.y, bv.z, bv.w};
#pragma unroll
            for (int i = 0; i < 8; ++i)
#pragma unroll
                for (int j = 0; j < 4; ++j) acc[i][j] = fmaf(a[i], b[j], acc[i][j]);
        }
        __syncthreads();
    }
#pragma unroll
    for (int i = 0; i < 8; ++i) {
        int row = m0 + tm * 8 + i;
        if (row < M) {
            float4 v = make_float4(acc[i][0], acc[i][1], acc[i][2], acc[i][3]);
            *reinterpret_cast<float4*>(&C[(size_t)row * Nn + n0 + tn * 4]) = v;
        }
    }
}

// ---------------- per-(node,head) attention scalars ----------------
template <int HEADS>
__global__ void attn_scores_k(const float* __restrict__ hin, const float* __restrict__ a_src,
                              const float* __restrict__ a_dst, float* __restrict__ esrc,
                              float* __restrict__ edst, int n) {
    int wid = blockIdx.x * (blockDim.x >> 6) + (threadIdx.x >> 6);
    int lane = threadIdx.x & 63;
    if (wid >= n * HEADS) return;
    int node = wid / HEADS;
    int h = wid - node * HEADS;
    float hv = hin[(size_t)node * (HEADS * 64) + h * 64 + lane];
    float vs = hv * a_src[h * 64 + lane];
    float vd = hv * a_dst[h * 64 + lane];
#pragma unroll
    for (int off = 32; off; off >>= 1) {
        vs += __shfl_xor(vs, off);
        vd += __shfl_xor(vd, off);
    }
    if (lane == 0) { esrc[wid] = vs; edst[wid] = vd; }
}

// ---------------- GAT aggregation (softmax + weighted gather) ----------------
// One block per destination node; thread = (head, channel). Softmax computed
// without max-subtraction (logits provably tiny => mathematically identical).
template <int HEADS>
__global__ void gat_aggregate_k(const float* __restrict__ hin, const float* __restrict__ esrc,
                                const float* __restrict__ edst, const int* __restrict__ rowptr,
                                const int* __restrict__ srcs, const float* __restrict__ bias,
                                float* __restrict__ gout, int n) {
    const int HC = HEADS * 64;
    int d = blockIdx.x;
    int tid = threadIdx.x;
    int h = tid >> 6;
    float ed = edst[d * HEADS + h];
    int lo = rowptr[d], hi = rowptr[d + 1];
    float den = 0.f, acc = 0.f;
    for (int i = lo; i < hi; ++i) {
        int s = srcs[i];
        float e = esrc[s * HEADS + h] + ed;
        e = (e >= 0.f) ? e : 0.2f * e;           // leaky_relu(0.2)
        float w = __expf(e);
        den += w;
        acc += w * hin[(size_t)s * HC + tid];
    }
    float o = acc / den + bias[tid];
    o = (o > 0.f) ? o : expm1f(o);               // ELU
    gout[(size_t)d * HC + tid] = o;
}

// ---------------- layer-3 aggregate fused with node attention gate ----------
// HEADS=1, blockDim=64: the block holds the whole node vector, so compute
// sigmoid(h.wp + bp) right here and store it.
__global__ void gat_aggregate1_attn_k(const float* __restrict__ hin, const float* __restrict__ esrc,
                                      const float* __restrict__ edst, const int* __restrict__ rowptr,
                                      const int* __restrict__ srcs, const float* __restrict__ bias,
                                      const float* __restrict__ wp, const float* __restrict__ bp,
                                      float* __restrict__ gout, float* __restrict__ attn, int n) {
    int d = blockIdx.x;
    int lane = threadIdx.x;                      // 0..63
    float ed = edst[d];
    int lo = rowptr[d], hi = rowptr[d + 1];
    float den = 0.f, acc = 0.f;
    for (int i = lo; i < hi; ++i) {
        int s = srcs[i];
        float e = esrc[s] + ed;
        e = (e >= 0.f) ? e : 0.2f * e;           // leaky_relu(0.2)
        float w = __expf(e);
        den += w;
        acc += w * hin[(size_t)s * 64 + lane];
    }
    float o = acc / den + bias[lane];
    o = (o > 0.f) ? o : expm1f(o);               // ELU
    gout[(size_t)d * 64 + lane] = o;
    float v = o * wp[lane];
#pragma unroll
    for (int off = 32; off; off >>= 1) v += __shfl_xor(v, off);
    if (lane == 0) attn[d] = 1.f / (1.f + __expf(-(v + bp[0])));
}

// ---------------- parallel segmented pooling (batch is sorted) ----------------
// Each wave run-length-accumulates a contiguous node range; one atomicAdd per
// (graph,channel) run it sees.
__global__ void pool_partial_k(const float* __restrict__ g3, const float* __restrict__ attn,
                               const int* __restrict__ batch, int n, float* __restrict__ sums) {
    int wid = blockIdx.x * (blockDim.x >> 6) + (threadIdx.x >> 6);
    int lane = threadIdx.x & 63;
    int nwaves = gridDim.x * (blockDim.x >> 6);
    int per = (n + nwaves - 1) / nwaves;
    int i0 = wid * per;
    int i1 = i0 + per;
    if (i1 > n) i1 = n;
    if (i0 >= i1) return;
    int cur = batch[i0];
    float acc = 0.f;
    for (int i = i0; i < i1; ++i) {
        int b = batch[i];
        if (b != cur) {
            atomicAdd(&sums[cur * 64 + lane], acc);
            acc = 0.f;
            cur = b;
        }
        acc += g3[(size_t)i * 64 + lane] * attn[i];
    }
    atomicAdd(&sums[cur * 64 + lane], acc);
}

// ---------------- final regressor: one block, wave per graph ----------------
__global__ void regress_k(const float* __restrict__ sums, const int* __restrict__ batch, int n,
                          const float* __restrict__ wr, const float* __restrict__ br,
                          float* __restrict__ out, int B) {
    int b = threadIdx.x >> 6;
    int lane = threadIdx.x & 63;
    if (b >= B) return;
    // count nodes with batch==b via two binary searches
    int lo = 0, hi = n;
    while (lo < hi) { int mid = (lo + hi) >> 1; if (batch[mid] < b) lo = mid + 1; else hi = mid; }
    int seg_lo = lo;
    lo = 0; hi = n;
    while (lo < hi) { int mid = (lo + hi) >> 1; if (batch[mid] < b + 1) lo = mid + 1; else hi = mid; }
    float cnt = (float)(lo - seg_lo);
    if (cnt < 1.f) cnt = 1.f;
    float v = (sums[b * 64 + lane] / cnt) * wr[lane];
#pragma unroll
    for (int off = 32; off; off >>= 1) v += __shfl_xor(v, off);
    if (lane == 0) out[b] = v + br[0];
}

// ---------------------------------------------------------------------------
extern "C" void kernel_launch(void* const* d_in, const int* in_sizes, int n_in,
                              void* d_out, int out_size, void* d_ws, size_t ws_size,
                              hipStream_t stream) {
    const float* x   = (const float*)d_in[0];
    const int*   ei  = (const int*)d_in[1];
    const int*   bat = (const int*)d_in[2];
    const float* W1  = (const float*)d_in[3];
    const float* as1 = (const float*)d_in[4];
    const float* ad1 = (const float*)d_in[5];
    const float* b1  = (const float*)d_in[6];
    const float* W2  = (const float*)d_in[7];
    const float* as2 = (const float*)d_in[8];
    const float* ad2 = (const float*)d_in[9];
    const float* b2  = (const float*)d_in[10];
    const float* W3  = (const float*)d_in[11];
    const float* as3 = (const float*)d_in[12];
    const float* ad3 = (const float*)d_in[13];
    const float* b3  = (const float*)d_in[14];
    const float* wp  = (const float*)d_in[15];
    const float* bp  = (const float*)d_in[16];
    const float* wr  = (const float*)d_in[17];
    const float* br  = (const float*)d_in[18];
    float* out = (float*)d_out;

    const int N    = in_sizes[2];          // 20000
    const int E    = in_sizes[1] / 2;      // 320000
    const int DIN  = in_sizes[0] / N;      // 128
    const int Etot = E + N;
    const int Bc   = out_size;             // 16

    char* ws = (char*)d_ws;
    size_t off = 0;
    auto alloc = [&](size_t bytes) {
        void* p = ws + off;
        off = (off + bytes + 255) & ~(size_t)255;
        return p;
    };
    int*   deg    = (int*)alloc((size_t)N * 4);
    int*   rowptr = (int*)alloc((size_t)(N + 1) * 4);
    int*   cursor = (int*)alloc((size_t)N * 4);
    int*   srcs   = (int*)alloc((size_t)Etot * 4);
    float* bufA   = (float*)alloc((size_t)N * 256 * 4);   // h1, then h2
    float* bufB   = (float*)alloc((size_t)N * 256 * 4);   // g1, then g2
    float* h3     = (float*)alloc((size_t)N * 64 * 4);
    float* g3     = (float*)alloc((size_t)N * 64 * 4);
    float* esrc   = (float*)alloc((size_t)N * 4 * 4);
    float* edst   = (float*)alloc((size_t)N * 4 * 4);
    float* attn   = (float*)alloc((size_t)N * 4);
    float* sums   = (float*)alloc((size_t)Bc * 64 * 4);
    (void)ws_size;

    // CSR build (shared by all layers)
    hipMemsetAsync(deg, 0, (size_t)N * 4, stream);
    int eb = (Etot + 255) / 256;
    edge_hist_k<<<eb, 256, 0, stream>>>(ei, E, N, deg);
    scan_excl_k<<<1, 256, 0, stream>>>(deg, rowptr, cursor, N);
    edge_scatter_k<<<eb, 256, 0, stream>>>(ei, E, N, cursor, srcs);

    dim3 gemm_grid1((N + 127) / 128, 256 / 64);
    dim3 gemm_grid3((N + 127) / 128, 1);

    // Layer 1: DIN -> (4,64) concat
    gemm_f32_k<<<gemm_grid1, 256, 0, stream>>>(x, W1, bufA, N, 256, DIN);
    attn_scores_k<4><<<(N * 4 + 3) / 4, 256, 0, stream>>>(bufA, as1, ad1, esrc, edst, N);
    gat_aggregate_k<4><<<N, 256, 0, stream>>>(bufA, esrc, edst, rowptr, srcs, b1, bufB, N);

    // Layer 2: 256 -> (4,64) concat
    gemm_f32_k<<<gemm_grid1, 256, 0, stream>>>(bufB, W2, bufA, N, 256, 256);
    attn_scores_k<4><<<(N * 4 + 3) / 4, 256, 0, stream>>>(bufA, as2, ad2, esrc, edst, N);
    gat_aggregate_k<4><<<N, 256, 0, stream>>>(bufA, esrc, edst, rowptr, srcs, b2, bufB, N);

    // Layer 3: 256 -> (1,64) mean + fused node-attention gate
    gemm_f32_k<<<gemm_grid3, 256, 0, stream>>>(bufB, W3, h3, N, 64, 256);
    attn_scores_k<1><<<(N + 3) / 4, 256, 0, stream>>>(h3, as3, ad3, esrc, edst, N);
    gat_aggregate1_attn_k<<<N, 64, 0, stream>>>(h3, esrc, edst, rowptr, srcs, b3, wp, bp, g3, attn, N);

    // Attention pool + regressor (parallel)
    hipMemsetAsync(sums, 0, (size_t)Bc * 64 * 4, stream);
    pool_partial_k<<<256, 256, 0, stream>>>(g3, attn, bat, N, sums);
    regress_k<<<1, 1024, 0, stream>>>(sums, bat, N, wr, br, out, Bc);
}

// Round 3
// 332.893 us; speedup vs baseline: 1.4777x; 1.2785x over previous
//
#include <hip/hip_runtime.h>

// ---------------------------------------------------------------------------
// GAT (3 layers) + attention pooling + regressor, full f32.
// N=20000 nodes, E=320000 edges (+N self loops), H=4 heads, C=64, B=16 graphs.
// ---------------------------------------------------------------------------

// ---------------- CSR-by-destination build ----------------
__global__ void edge_hist_k(const int* __restrict__ ei, int E, int n, int* __restrict__ deg) {
    int i = blockIdx.x * blockDim.x + threadIdx.x;
    if (i >= E + n) return;
    int dst = (i < E) ? ei[E + i] : (i - E);   // self-loop for i >= E
    atomicAdd(&deg[dst], 1);
}

__global__ __launch_bounds__(1024) void scan_excl_k(const int* __restrict__ deg, int* __restrict__ rowptr,
                                                    int* __restrict__ cursor, int n) {
    __shared__ int part[1024];
    int tid = threadIdx.x;
    int chunk = (n + 1023) / 1024;
    int lo = tid * chunk;
    int hi = lo + chunk;
    if (lo > n) lo = n;
    if (hi > n) hi = n;
    int s = 0;
    for (int i = lo; i < hi; ++i) s += deg[i];
    part[tid] = s;
    __syncthreads();
    for (int off = 1; off < 1024; off <<= 1) {
        int v = (tid >= off) ? part[tid - off] : 0;
        __syncthreads();
        part[tid] += v;
        __syncthreads();
    }
    int run = (tid == 0) ? 0 : part[tid - 1];
    for (int i = lo; i < hi; ++i) {
        rowptr[i] = run;
        cursor[i] = run;
        run += deg[i];
    }
    if (tid == 1023) rowptr[n] = run;
}

__global__ void edge_scatter_k(const int* __restrict__ ei, int E, int n,
                               int* __restrict__ cursor, int* __restrict__ srcs) {
    int i = blockIdx.x * blockDim.x + threadIdx.x;
    if (i >= E + n) return;
    int src, dst;
    if (i < E) { src = ei[i]; dst = ei[E + i]; }
    else       { src = i - E; dst = src; }
    int pos = atomicAdd(&cursor[dst], 1);
    srcs[pos] = src;
}

// ---------------- f32 tiled GEMM: C[M,Nn] = A[M,K] @ B[K,Nn] ----------------
__global__ __launch_bounds__(256) void gemm_f32_k(const float* __restrict__ A,
                                                  const float* __restrict__ B,
                                                  float* __restrict__ C,
                                                  int M, int Nn, int K) {
    __shared__ float As[16][128];   // A transposed: As[k][m]
    __shared__ float Bs[16][64];
    const int tid = threadIdx.x;
    const int m0 = blockIdx.x * 128;
    const int n0 = blockIdx.y * 64;
    const int tm = tid >> 4;        // 0..15
    const int tn = tid & 15;        // 0..15
    float acc[8][4];
#pragma unroll
    for (int i = 0; i < 8; ++i)
#pragma unroll
        for (int j = 0; j < 4; ++j) acc[i][j] = 0.f;

    for (int k0 = 0; k0 < K; k0 += 16) {
#pragma unroll
        for (int i = 0; i < 2; ++i) {
            int f = tid * 2 + i;
            int r = f >> 2;
            int kq = (f & 3) << 2;
            int row = m0 + r;
            float4 v = make_float4(0.f, 0.f, 0.f, 0.f);
            if (row < M) v = *reinterpret_cast<const float4*>(&A[(size_t)row * K + k0 + kq]);
            As[kq + 0][r] = v.x;
            As[kq + 1][r] = v.y;
            As[kq + 2][r] = v.z;
            As[kq + 3][r] = v.w;
        }
        {
            int kk = tid >> 4;
            int cq = (tid & 15) << 2;
            *reinterpret_cast<float4*>(&Bs[kk][cq]) =
                *reinterpret_cast<const float4*>(&B[(size_t)(k0 + kk) * Nn + n0 + cq]);
        }
        __syncthreads();
#pragma unroll
        for (int k = 0; k < 16; ++k) {
            float4 a0 = *reinterpret_cast<const float4*>(&As[k][tm * 8]);
            float4 a1 = *reinterpret_cast<const float4*>(&As[k][tm * 8 + 4]);
            float4 bv = *reinterpret_cast<const float4*>(&Bs[k][tn * 4]);
            float a[8] = {a0.x, a0.y, a0.z, a0.w, a1.x, a1.y, a1.z, a1.w};
            float b[4] = {bv.x, bv.y, bv.z, bv.w};
#pragma unroll
            for (int i = 0; i < 8; ++i)
#pragma unroll
                for (int j = 0; j < 4; ++j) acc[i][j] = fmaf(a[i], b[j], acc[i][j]);
        }
        __syncthreads();
    }
#pragma unroll
    for (int i = 0; i < 8; ++i) {
        int row = m0 + tm * 8 + i;
        if (row < M) {
            float4 v = make_float4(acc[i][0], acc[i][1], acc[i][2], acc[i][3]);
            *reinterpret_cast<float4*>(&C[(size_t)row * Nn + n0 + tn * 4]) = v;
        }
    }
}

// ---------------- per-(node,head) attention scalars ----------------
// HEADS==4: one wave per node, float4 loads, 16-lane group reduce per head.
__global__ void attn_scores4_k(const float* __restrict__ hin, const float* __restrict__ a_src,
                               const float* __restrict__ a_dst, float* __restrict__ esrc,
                               float* __restrict__ edst, int n) {
    int node = blockIdx.x * 4 + (threadIdx.x >> 6);
    int lane = threadIdx.x & 63;
    if (node >= n) return;
    float4 hv  = *reinterpret_cast<const float4*>(&hin[(size_t)node * 256 + lane * 4]);
    float4 asv = *reinterpret_cast<const float4*>(&a_src[lane * 4]);
    float4 adv = *reinterpret_cast<const float4*>(&a_dst[lane * 4]);
    float vs = hv.x * asv.x + hv.y * asv.y + hv.z * asv.z + hv.w * asv.w;
    float vd = hv.x * adv.x + hv.y * adv.y + hv.z * adv.z + hv.w * adv.w;
#pragma unroll
    for (int off = 8; off; off >>= 1) {         // reduce within 16-lane (per-head) group
        vs += __shfl_xor(vs, off);
        vd += __shfl_xor(vd, off);
    }
    if ((lane & 15) == 0) {
        int h = lane >> 4;
        esrc[node * 4 + h] = vs;
        edst[node * 4 + h] = vd;
    }
}

// HEADS==1: one wave per node, 64-lane reduce.
__global__ void attn_scores1_k(const float* __restrict__ hin, const float* __restrict__ a_src,
                               const float* __restrict__ a_dst, float* __restrict__ esrc,
                               float* __restrict__ edst, int n) {
    int node = blockIdx.x * 4 + (threadIdx.x >> 6);
    int lane = threadIdx.x & 63;
    if (node >= n) return;
    float hv = hin[(size_t)node * 64 + lane];
    float vs = hv * a_src[lane];
    float vd = hv * a_dst[lane];
#pragma unroll
    for (int off = 32; off; off >>= 1) {
        vs += __shfl_xor(vs, off);
        vd += __shfl_xor(vd, off);
    }
    if (lane == 0) { esrc[node] = vs; edst[node] = vd; }
}

// ---------------- GAT aggregation, HEADS=4: one wave per dst node ----------
// lane l holds channels 4l..4l+3 (head = l>>4). srcs batched via lanes +
// __shfl broadcast; 1-deep prefetch of next edge's esrc + h row.
__global__ __launch_bounds__(256) void gat_aggregate4_k(
        const float* __restrict__ hin, const float* __restrict__ esrc,
        const float* __restrict__ edst, const int* __restrict__ rowptr,
        const int* __restrict__ srcs, const float* __restrict__ bias,
        float* __restrict__ gout, int n) {
    int d = blockIdx.x * 4 + (threadIdx.x >> 6);
    int lane = threadIdx.x & 63;
    if (d >= n) return;
    int hh = lane >> 4;
    float ed = edst[d * 4 + hh];
    int lo = rowptr[d], hi = rowptr[d + 1];
    float4 acc = make_float4(0.f, 0.f, 0.f, 0.f);
    float den = 0.f;
    for (int base = lo; base < hi; base += 64) {
        int cnt = min(64, hi - base);
        int sv = (lane < cnt) ? srcs[base + lane] : 0;
        int s0 = __shfl(sv, 0);
        float es_nxt = esrc[s0 * 4 + hh];
        float4 h_nxt = *reinterpret_cast<const float4*>(&hin[(size_t)s0 * 256 + lane * 4]);
        for (int j = 0; j < cnt; ++j) {
            float es = es_nxt;
            float4 hv = h_nxt;
            if (j + 1 < cnt) {
                int s1 = __shfl(sv, j + 1);
                es_nxt = esrc[s1 * 4 + hh];
                h_nxt = *reinterpret_cast<const float4*>(&hin[(size_t)s1 * 256 + lane * 4]);
            }
            float e = es + ed;
            e = (e >= 0.f) ? e : 0.2f * e;       // leaky_relu(0.2)
            float w = __expf(e);
            den += w;
            acc.x = fmaf(w, hv.x, acc.x);
            acc.y = fmaf(w, hv.y, acc.y);
            acc.z = fmaf(w, hv.z, acc.z);
            acc.w = fmaf(w, hv.w, acc.w);
        }
    }
    float inv = 1.f / den;
    float4 bv = *reinterpret_cast<const float4*>(&bias[lane * 4]);
    float4 o;
    o.x = acc.x * inv + bv.x;
    o.y = acc.y * inv + bv.y;
    o.z = acc.z * inv + bv.z;
    o.w = acc.w * inv + bv.w;
    o.x = (o.x > 0.f) ? o.x : expm1f(o.x);       // ELU
    o.y = (o.y > 0.f) ? o.y : expm1f(o.y);
    o.z = (o.z > 0.f) ? o.z : expm1f(o.z);
    o.w = (o.w > 0.f) ? o.w : expm1f(o.w);
    *reinterpret_cast<float4*>(&gout[(size_t)d * 256 + lane * 4]) = o;
}

// ---------------- layer-3 aggregate (1 head) fused with node attn gate ------
// One wave per dst node (4 per block); lane = channel; srcs batch + prefetch.
__global__ __launch_bounds__(256) void gat_aggregate1_attn_k(
        const float* __restrict__ hin, const float* __restrict__ esrc,
        const float* __restrict__ edst, const int* __restrict__ rowptr,
        const int* __restrict__ srcs, const float* __restrict__ bias,
        const float* __restrict__ wp, const float* __restrict__ bp,
        float* __restrict__ gout, float* __restrict__ attn, int n) {
    int d = blockIdx.x * 4 + (threadIdx.x >> 6);
    int lane = threadIdx.x & 63;
    if (d >= n) return;
    float ed = edst[d];
    int lo = rowptr[d], hi = rowptr[d + 1];
    float den = 0.f, acc = 0.f;
    for (int base = lo; base < hi; base += 64) {
        int cnt = min(64, hi - base);
        int sv = (lane < cnt) ? srcs[base + lane] : 0;
        int s0 = __shfl(sv, 0);
        float es_nxt = esrc[s0];
        float h_nxt = hin[(size_t)s0 * 64 + lane];
        for (int j = 0; j < cnt; ++j) {
            float es = es_nxt;
            float hv = h_nxt;
            if (j + 1 < cnt) {
                int s1 = __shfl(sv, j + 1);
                es_nxt = esrc[s1];
                h_nxt = hin[(size_t)s1 * 64 + lane];
            }
            float e = es + ed;
            e = (e >= 0.f) ? e : 0.2f * e;
            float w = __expf(e);
            den += w;
            acc = fmaf(w, hv, acc);
        }
    }
    float o = acc / den + bias[lane];
    o = (o > 0.f) ? o : expm1f(o);               // ELU
    gout[(size_t)d * 64 + lane] = o;
    float v = o * wp[lane];
#pragma unroll
    for (int off = 32; off; off >>= 1) v += __shfl_xor(v, off);
    if (lane == 0) attn[d] = 1.f / (1.f + __expf(-(v + bp[0])));
}

// ---------------- parallel segmented pooling (batch is sorted) --------------
__global__ void pool_partial_k(const float* __restrict__ g3, const float* __restrict__ attn,
                               const int* __restrict__ batch, int n, float* __restrict__ sums) {
    int wid = blockIdx.x * (blockDim.x >> 6) + (threadIdx.x >> 6);
    int lane = threadIdx.x & 63;
    int nwaves = gridDim.x * (blockDim.x >> 6);
    int per = (n + nwaves - 1) / nwaves;
    int i0 = wid * per;
    int i1 = i0 + per;
    if (i1 > n) i1 = n;
    if (i0 >= i1) return;
    int cur = batch[i0];
    float acc = 0.f;
    for (int i = i0; i < i1; ++i) {
        int b = batch[i];
        if (b != cur) {
            atomicAdd(&sums[cur * 64 + lane], acc);
            acc = 0.f;
            cur = b;
        }
        acc += g3[(size_t)i * 64 + lane] * attn[i];
    }
    atomicAdd(&sums[cur * 64 + lane], acc);
}

// ---------------- final regressor: one block, wave per graph ----------------
__global__ void regress_k(const float* __restrict__ sums, const int* __restrict__ batch, int n,
                          const float* __restrict__ wr, const float* __restrict__ br,
                          float* __restrict__ out, int B) {
    int b = threadIdx.x >> 6;
    int lane = threadIdx.x & 63;
    if (b >= B) return;
    int lo = 0, hi = n;
    while (lo < hi) { int mid = (lo + hi) >> 1; if (batch[mid] < b) lo = mid + 1; else hi = mid; }
    int seg_lo = lo;
    lo = 0; hi = n;
    while (lo < hi) { int mid = (lo + hi) >> 1; if (batch[mid] < b + 1) lo = mid + 1; else hi = mid; }
    float cnt = (float)(lo - seg_lo);
    if (cnt < 1.f) cnt = 1.f;
    float v = (sums[b * 64 + lane] / cnt) * wr[lane];
#pragma unroll
    for (int off = 32; off; off >>= 1) v += __shfl_xor(v, off);
    if (lane == 0) out[b] = v + br[0];
}

// ---------------------------------------------------------------------------
extern "C" void kernel_launch(void* const* d_in, const int* in_sizes, int n_in,
                              void* d_out, int out_size, void* d_ws, size_t ws_size,
                              hipStream_t stream) {
    const float* x   = (const float*)d_in[0];
    const int*   ei  = (const int*)d_in[1];
    const int*   bat = (const int*)d_in[2];
    const float* W1  = (const float*)d_in[3];
    const float* as1 = (const float*)d_in[4];
    const float* ad1 = (const float*)d_in[5];
    const float* b1  = (const float*)d_in[6];
    const float* W2  = (const float*)d_in[7];
    const float* as2 = (const float*)d_in[8];
    const float* ad2 = (const float*)d_in[9];
    const float* b2  = (const float*)d_in[10];
    const float* W3  = (const float*)d_in[11];
    const float* as3 = (const float*)d_in[12];
    const float* ad3 = (const float*)d_in[13];
    const float* b3  = (const float*)d_in[14];
    const float* wp  = (const float*)d_in[15];
    const float* bp  = (const float*)d_in[16];
    const float* wr  = (const float*)d_in[17];
    const float* br  = (const float*)d_in[18];
    float* out = (float*)d_out;

    const int N    = in_sizes[2];          // 20000
    const int E    = in_sizes[1] / 2;      // 320000
    const int DIN  = in_sizes[0] / N;      // 128
    const int Etot = E + N;
    const int Bc   = out_size;             // 16

    char* ws = (char*)d_ws;
    size_t off = 0;
    auto alloc = [&](size_t bytes) {
        void* p = ws + off;
        off = (off + bytes + 255) & ~(size_t)255;
        return p;
    };
    int*   deg    = (int*)alloc((size_t)N * 4);
    int*   rowptr = (int*)alloc((size_t)(N + 1) * 4);
    int*   cursor = (int*)alloc((size_t)N * 4);
    int*   srcs   = (int*)alloc((size_t)Etot * 4);
    float* bufA   = (float*)alloc((size_t)N * 256 * 4);   // h1, then h2
    float* bufB   = (float*)alloc((size_t)N * 256 * 4);   // g1, then g2
    float* h3     = (float*)alloc((size_t)N * 64 * 4);
    float* g3     = (float*)alloc((size_t)N * 64 * 4);
    float* esrc   = (float*)alloc((size_t)N * 4 * 4);
    float* edst   = (float*)alloc((size_t)N * 4 * 4);
    float* attn   = (float*)alloc((size_t)N * 4);
    float* sums   = (float*)alloc((size_t)Bc * 64 * 4);
    (void)ws_size;

    // CSR build (shared by all layers)
    hipMemsetAsync(deg, 0, (size_t)N * 4, stream);
    int eb = (Etot + 255) / 256;
    edge_hist_k<<<eb, 256, 0, stream>>>(ei, E, N, deg);
    scan_excl_k<<<1, 1024, 0, stream>>>(deg, rowptr, cursor, N);
    edge_scatter_k<<<eb, 256, 0, stream>>>(ei, E, N, cursor, srcs);

    dim3 gemm_grid1((N + 127) / 128, 256 / 64);
    dim3 gemm_grid3((N + 127) / 128, 1);
    int nb4 = (N + 3) / 4;

    // Layer 1: DIN -> (4,64) concat
    gemm_f32_k<<<gemm_grid1, 256, 0, stream>>>(x, W1, bufA, N, 256, DIN);
    attn_scores4_k<<<nb4, 256, 0, stream>>>(bufA, as1, ad1, esrc, edst, N);
    gat_aggregate4_k<<<nb4, 256, 0, stream>>>(bufA, esrc, edst, rowptr, srcs, b1, bufB, N);

    // Layer 2: 256 -> (4,64) concat
    gemm_f32_k<<<gemm_grid1, 256, 0, stream>>>(bufB, W2, bufA, N, 256, 256);
    attn_scores4_k<<<nb4, 256, 0, stream>>>(bufA, as2, ad2, esrc, edst, N);
    gat_aggregate4_k<<<nb4, 256, 0, stream>>>(bufA, esrc, edst, rowptr, srcs, b2, bufB, N);

    // Layer 3: 256 -> (1,64) mean + fused node-attention gate
    gemm_f32_k<<<gemm_grid3, 256, 0, stream>>>(bufB, W3, h3, N, 64, 256);
    attn_scores1_k<<<nb4, 256, 0, stream>>>(h3, as3, ad3, esrc, edst, N);
    gat_aggregate1_attn_k<<<nb4, 256, 0, stream>>>(h3, esrc, edst, rowptr, srcs, b3, wp, bp, g3, attn, N);

    // Attention pool + regressor (parallel)
    hipMemsetAsync(sums, 0, (size_t)Bc * 64 * 4, stream);
    pool_partial_k<<<256, 256, 0, stream>>>(g3, attn, bat, N, sums);
    regress_k<<<1, 1024, 0, stream>>>(sums, bat, N, wr, br, out, Bc);
}